// Round 15
// baseline (468.605 us; speedup 1.0000x reference)
//
#include <hip/hip_runtime.h>
#include <stdint.h>

typedef unsigned short u16;
typedef __attribute__((ext_vector_type(8))) __bf16 bf16x8;
typedef __attribute__((ext_vector_type(4))) float f32x4;

// ---------- helpers ----------
__device__ __forceinline__ u16 f2bf(float f) {  // RNE fp32 -> bf16
  unsigned int u = __builtin_bit_cast(unsigned int, f);
  u = (u + 0x7FFFu + ((u >> 16) & 1u)) >> 16;
  return (u16)u;
}
// 8 ternary i8 (two's complement) -> 8 bf16. 1->0x3F80, 0xFF->0xBF80, 0->0.
__device__ __forceinline__ bf16x8 expand8(unsigned q0, unsigned q1) {
  unsigned x = (q0 & 0xFFu) | ((q0 & 0xFF00u) << 8);
  unsigned y = ((q0 >> 16) & 0xFFu) | ((q0 >> 8) & 0xFF0000u);
  unsigned z = (q1 & 0xFFu) | ((q1 & 0xFF00u) << 8);
  unsigned w = ((q1 >> 16) & 0xFFu) | ((q1 >> 8) & 0xFF0000u);
  uint4 o;
  o.x = ((x & 0x10001u) * 0x3F80u) | ((x & 0x800080u) << 8);
  o.y = ((y & 0x10001u) * 0x3F80u) | ((y & 0x800080u) << 8);
  o.z = ((z & 0x10001u) * 0x3F80u) | ((z & 0x800080u) << 8);
  o.w = ((w & 0x10001u) * 0x3F80u) | ((w & 0x800080u) << 8);
  return __builtin_bit_cast(bf16x8, o);
}

#define GLOAD_LDS16(g, l)                                                          \
  __builtin_amdgcn_global_load_lds((__attribute__((address_space(1))) void*)(g),   \
                                   (__attribute__((address_space(3))) void*)(l),   \
                                   16, 0, 0)

// ---------- problem sizes ----------
#define M_TOK 8192
#define N_OUT 4096
#define K_IN  4096
#define RANK  32

// ---------- ws layout (bytes) ----------
#define WS_XB    0ull
#define WS_WB    67108864ull   // W i8 permuted [4096][4096] (16MB)
#define WS_BB    100663296ull
#define WS_A32   100925440ull
#define WS_T32   101187584ull
#define WS_TPART 101711872ull
#define WS_FLAG  110100480ull

// ---------- prep kernels ----------
__global__ void k_convert_x(const float4* __restrict__ x, ushort4* __restrict__ xb, int n4) {
  int stride = gridDim.x * blockDim.x;
  for (int i = blockIdx.x * blockDim.x + threadIdx.x; i < n4; i += stride) {
    float4 v = x[i];
    ushort4 o;
    o.x = f2bf(v.x); o.y = f2bf(v.y); o.z = f2bf(v.z); o.w = f2bf(v.w);
    xb[i] = o;
  }
}

__global__ void k_detect_wtype(const int* __restrict__ w, int* __restrict__ flag) {
  int v = w[threadIdx.x];
  bool ok = (v >= -1 && v <= 1);
  unsigned long long m = __ballot(ok);
  if (threadIdx.x == 0) *flag = (m == ~0ull) ? 1 : 0;
}

// W -> i8, k-permuted within each 64-group: orig j = kh*8+s+32h (kh<4,h<2,s<8)
// stored at p = kh*16 + h*8 + s, so one 16B LDS chunk at kh holds both K32
// sub-tiles' 8B fragments for a lane.
__global__ void k_convert_w8(const void* __restrict__ wq, const int* __restrict__ flag,
                             char* __restrict__ wb8) {
  int is32 = *flag;
  int stride = gridDim.x * blockDim.x;
  int total = N_OUT * K_IN / 8;
  for (int i = blockIdx.x * blockDim.x + threadIdx.x; i < total; i += stride) {
    int row = i >> 9;
    int jb = (i & 511) * 8;
    uint2 pk;
    if (is32) {
      const int* s = (const int*)wq + (size_t)row * K_IN + jb;
      unsigned lo = 0, hi = 0;
#pragma unroll
      for (int k2 = 0; k2 < 4; ++k2) lo |= ((unsigned)s[k2] & 0xFFu) << (8 * k2);
#pragma unroll
      for (int k2 = 0; k2 < 4; ++k2) hi |= ((unsigned)s[4 + k2] & 0xFFu) << (8 * k2);
      pk.x = lo; pk.y = hi;
    } else {
      pk = *(const uint2*)((const char*)wq + (size_t)row * K_IN + jb);
    }
    int jin = jb & 63, g = jb >> 6;
    int p = ((jin >> 3) & 3) * 16 + (jin >> 5) * 8;
    *(uint2*)(wb8 + (size_t)row * K_IN + (g << 6) + p) = pk;
  }
}

__global__ void k_prep_B(const float* __restrict__ loraB, u16* __restrict__ bb) {
  int idx = blockIdx.x * blockDim.x + threadIdx.x;
  if (idx < RANK * K_IN) bb[idx] = f2bf(loraB[idx]);
}

__global__ void k_prep_A(const float* __restrict__ loraA, const float* __restrict__ scale,
                         u16* __restrict__ a32) {
  int idx = blockIdx.x * blockDim.x + threadIdx.x;
  if (idx >= N_OUT * RANK) return;
  int o = idx >> 5;
  a32[idx] = f2bf(loraA[idx] / scale[o]);
}

// ---------- T = x @ B^T (MFMA; 1024 blocks) ----------
__global__ __launch_bounds__(256) void k_lora_T(const u16* __restrict__ xb,
                                                const u16* __restrict__ bb,
                                                float* __restrict__ tpart) {
  __shared__ u16 As[64 * 32];
  __shared__ u16 Bs[32 * 32];
  int mt = blockIdx.x >> 3;
  int ks = blockIdx.x & 7;
  int tid = threadIdx.x, lane = tid & 63, wv = tid >> 6;
  int m0 = mt * 64;
  int kbase0 = ks * 512;
  f32x4 acc[2] = {};
  for (int step = 0; step < 16; ++step) {
    int kb = kbase0 + step * 32;
    __syncthreads();
    {
      const u16* src = xb + (size_t)(m0 + (tid >> 2)) * K_IN + kb + (tid & 3) * 8;
      GLOAD_LDS16(src, &As[tid * 8]);
    }
    if (tid < 128) {
      const u16* src = bb + (size_t)(tid >> 2) * K_IN + kb + (tid & 3) * 8;
      GLOAD_LDS16(src, &Bs[tid * 8]);
    }
    __syncthreads();
    bf16x8 a = *(const bf16x8*)&As[(wv * 16 + (lane & 15)) * 32 + (lane >> 4) * 8];
#pragma unroll
    for (int ni = 0; ni < 2; ++ni) {
      bf16x8 b = *(const bf16x8*)&Bs[(ni * 16 + (lane & 15)) * 32 + (lane >> 4) * 8];
      acc[ni] = __builtin_amdgcn_mfma_f32_16x16x32_bf16(a, b, acc[ni], 0, 0, 0);
    }
  }
#pragma unroll
  for (int ni = 0; ni < 2; ++ni)
#pragma unroll
    for (int r = 0; r < 4; ++r) {
      int row = m0 + wv * 16 + (lane >> 4) * 4 + r;
      int col = ni * 16 + (lane & 15);
      tpart[((size_t)ks * M_TOK + row) * RANK + col] = acc[ni][r];
    }
}

__global__ void k_reduce_T(const float* __restrict__ tpart, u16* __restrict__ t32) {
  int idx = blockIdx.x * blockDim.x + threadIdx.x;
  if (idx >= M_TOK * RANK) return;
  int t = idx >> 5, r = idx & 31;
  float v = 0.f;
#pragma unroll
  for (int s = 0; s < 8; ++s) v += tpart[((size_t)s * M_TOK + t) * RANK + r];
  t32[idx] = f2bf(v);
}

// ---------- main GEMM: 256x256, BK=32, 16 waves, i8 B-path ----------
// R12 skeleton + B as i8 K64-pairs (ring-4 x 16KB, one w16 gload per pair at
// even tiles). One b128 B-read per nj per PAIR (k-permuted layout) yields both
// K32 sub-tiles; h0 expanded now, h1 stashed raw. LDS/tile 160->120KB. B rows
// 64B -> verified swizzle family unchanged. Waits: steady W2 (even)/W1 (odd);
// invariant: end-of-t wait => stages for tiles <= t+2 landed; barrier
// publishes for the pre-barrier read-ahead of t+1. LoRA-B (floats) staged
// bf16 into Bs8 slot 1 (free after its last pair use at t=121).
__global__ __launch_bounds__(1024, 4) void k_gemm8(const u16* __restrict__ xb,
                                                   const char* __restrict__ wb8,
                                                   const u16* __restrict__ t32,
                                                   const u16* __restrict__ a32,
                                                   const float* __restrict__ scale,
                                                   const float* __restrict__ bias,
                                                   float* __restrict__ out) {
  __shared__ u16 As[4][8192];     // 64KB
  __shared__ char Bs8[4][16384];  // 64KB
  const int tid = threadIdx.x;
  const int l = tid & 63, w = tid >> 6;
  const int wm = w >> 2, wn = w & 3;
  const int bid = blockIdx.x;
  const int swz = (bid & 7) * 64 + (bid >> 3);
  const int m0 = (swz >> 4) * 256, n0 = (swz & 15) * 256;

  const int srow = tid >> 2;
  const int scx = ((tid & 3) ^ ((tid >> 3) & 3)) * 8;   // u16 units
  const int ldst = tid * 8;                              // u16 units
  const int r15 = l & 15;
  const int cxr = (((l >> 4) ^ ((r15 >> 1) & 3)) * 8);   // u16 units
  const int cxB = (((l >> 4) ^ ((r15 >> 1) & 3)) * 16);  // bytes

  f32x4 acc[4][4] = {};

  u16* AsF = &As[0][0];
  char* Bs8F = &Bs8[0][0];
  const u16* axs = xb + (size_t)(m0 + srow) * K_IN + scx;
  const char* bsrc = wb8 + (size_t)(n0 + (tid >> 2)) * 4096 +
                     (size_t)(((tid & 3) ^ ((tid >> 3) & 3)) * 16);

  // prologue: B pairs 0,1 -> slots 0,1; A tiles 0,1,2 -> slots 0,1,2
  GLOAD_LDS16(bsrc, Bs8F + 0 * 16384 + tid * 16); bsrc += 64;
  GLOAD_LDS16(bsrc, Bs8F + 1 * 16384 + tid * 16); bsrc += 64;
#pragma unroll
  for (int ts = 0; ts < 3; ++ts) GLOAD_LDS16(axs + ts * 32, AsF + ts * 8192 + ldst);
  asm volatile("s_waitcnt vmcnt(1)" ::: "memory");  // all but A2 landed
  asm volatile("s_barrier" ::: "memory");

  const int abase = (wm * 64 + r15) * 32 + cxr;
  const int bb8base = (wn * 64 + r15) * 64 + cxB;  // nj stride 1024 bytes
  const int lbbase = (wn * 64 + r15) * 32 + cxr;   // nj stride 512 u16

  const u16* ap = axs + 96;  // -> tile 3

  bf16x8 fa[4], fb[4];
  uint2 stash[4];

#define SA(DST) { GLOAD_LDS16(ap, AsF + (DST) * 8192 + ldst); ap += 32; }
#define SBP(DST) { GLOAD_LDS16(bsrc, Bs8F + (DST) * 16384 + tid * 16); bsrc += 64; }
#define SLB { GLOAD_LDS16(a32 + (size_t)(n0 + srow) * RANK + scx, Bs8F + 16384 + ldst * 2); }
#define SAL { GLOAD_LDS16(t32 + (size_t)(m0 + srow) * RANK + scx, AsF + 0 * 8192 + ldst); }
#define W2  asm volatile("s_waitcnt vmcnt(2)" ::: "memory");
#define W1  asm volatile("s_waitcnt vmcnt(1)" ::: "memory");
#define W0  asm volatile("s_waitcnt vmcnt(0)" ::: "memory");
#define BARR asm volatile("s_barrier" ::: "memory");
#define RDE(NS, BS)                                                                 \
  { const u16* An = AsF + (NS) * 8192;                                              \
    _Pragma("unroll") for (int mi = 0; mi < 4; ++mi)                                \
        fa[mi] = *(const bf16x8*)&An[abase + mi * 512];                             \
    const char* Bn = Bs8F + (BS) * 16384;                                           \
    _Pragma("unroll") for (int nj = 0; nj < 4; ++nj) {                              \
      uint4 r_ = *(const uint4*)&Bn[bb8base + nj * 1024];                           \
      fb[nj] = expand8(r_.x, r_.y);                                                 \
      stash[nj] = make_uint2(r_.z, r_.w); } }
#define RDO(NS)                                                                     \
  { const u16* An = AsF + (NS) * 8192;                                              \
    _Pragma("unroll") for (int mi = 0; mi < 4; ++mi)                                \
        fa[mi] = *(const bf16x8*)&An[abase + mi * 512];                             \
    _Pragma("unroll") for (int nj = 0; nj < 4; ++nj)                                \
        fb[nj] = expand8(stash[nj].x, stash[nj].y); }
#define RDL                                                                         \
  { const u16* An = AsF;                                                            \
    _Pragma("unroll") for (int mi = 0; mi < 4; ++mi)                                \
        fa[mi] = *(const bf16x8*)&An[abase + mi * 512];                             \
    const u16* Ln = (const u16*)(Bs8F + 16384);                                     \
    _Pragma("unroll") for (int nj = 0; nj < 4; ++nj)                                \
        fb[nj] = *(const bf16x8*)&Ln[lbbase + nj * 512]; }

#define TILE(STAGE, WAIT, RD)                                                       \
  {                                                                                 \
    STAGE                                                                           \
    __builtin_amdgcn_s_setprio(1);                                                  \
    _Pragma("unroll") for (int mi = 0; mi < 4; ++mi)                                \
    _Pragma("unroll") for (int nj = 0; nj < 4; ++nj)                                \
        acc[mi][nj] =                                                               \
            __builtin_amdgcn_mfma_f32_16x16x32_bf16(fa[mi], fb[nj], acc[mi][nj], 0, 0, 0); \
    __builtin_amdgcn_s_setprio(0);                                                  \
    WAIT                                                                            \
    RD                                                                              \
    BARR                                                                            \
  }

  RDE(0, 0)  // tile 0 frags (published by prologue barrier)

  // main loop: tiles 0..119; A stages 3..122; B pairs 2..61 at even tiles
#pragma unroll 1
  for (int it = 0; it < 15; ++it) {
    TILE(SA(3) SBP(2), W2, RDO(1))    // t%8=0
    TILE(SA(0),        W1, RDE(2, 1)) // t%8=1
    TILE(SA(1) SBP(3), W2, RDO(3))    // t%8=2
    TILE(SA(2),        W1, RDE(0, 2)) // t%8=3
    TILE(SA(3) SBP(0), W2, RDO(1))    // t%8=4
    TILE(SA(0),        W1, RDE(2, 3)) // t%8=5
    TILE(SA(1) SBP(1), W2, RDO(3))    // t%8=6
    TILE(SA(2),        W1, RDE(0, 0)) // t%8=7
  }
  // tail: tiles 120..128 (128 = LoRA)
  TILE(SA(3) SBP(2), W2, RDO(1))      // t=120: stage A123, pair62(slot2)
  TILE(SA(0),        W1, RDE(2, 1))   // t=121: stage A124; read pair61
  TILE(SA(1) SBP(3), W2, RDO(3))      // t=122: stage A125, pair63(slot3)
  TILE(SA(2),        W1, RDE(0, 2))   // t=123: stage A126; read pair62
  TILE(SA(3) SLB,    W2, RDO(1))      // t=124: stage A127 + LoRA-B(bf16->slot1)
  TILE(SAL,          W2, RDE(2, 3))   // t=125: stage LoRA-A->A-slot0; read pair63
  TILE(,             W0, RDO(3))      // t=126: drain; t127 frags (stash + A s3)
  TILE(,             ,   RDL)         // t=127: LoRA frags
  TILE(,             ,   )            // t=128: LoRA tile

  // epilogue: out = acc*scale[col] + bias[col]
#pragma unroll
  for (int nj = 0; nj < 4; ++nj) {
    int col = n0 + wn * 64 + nj * 16 + r15;
    float s = scale[col], bv = bias[col];
#pragma unroll
    for (int mi = 0; mi < 4; ++mi) {
      int row = m0 + wm * 64 + mi * 16 + (l >> 4) * 4;
#pragma unroll
      for (int r = 0; r < 4; ++r)
        out[(size_t)(row + r) * N_OUT + col] = acc[mi][nj][r] * s + bv;
    }
  }
}

// ---------- launch ----------
extern "C" void kernel_launch(void* const* d_in, const int* in_sizes, int n_in,
                              void* d_out, int out_size, void* d_ws, size_t ws_size,
                              hipStream_t stream) {
  const float* x     = (const float*)d_in[0];
  const void*  wq    = d_in[1];
  const float* scale = (const float*)d_in[2];
  const float* loraA = (const float*)d_in[3];
  const float* loraB = (const float*)d_in[4];
  const float* bias  = (const float*)d_in[5];
  float* out = (float*)d_out;

  char* ws = (char*)d_ws;
  u16*   xb    = (u16*)(ws + WS_XB);
  char*  wb8   = (char*)(ws + WS_WB);
  u16*   bb    = (u16*)(ws + WS_BB);
  u16*   a32   = (u16*)(ws + WS_A32);
  u16*   t32   = (u16*)(ws + WS_T32);
  float* tpart = (float*)(ws + WS_TPART);
  int*   flag  = (int*)(ws + WS_FLAG);

  k_convert_x<<<2048, 256, 0, stream>>>((const float4*)x, (ushort4*)xb, M_TOK * K_IN / 4);
  k_detect_wtype<<<1, 64, 0, stream>>>((const int*)wq, flag);
  k_prep_B<<<512, 256, 0, stream>>>(loraB, bb);
  k_prep_A<<<512, 256, 0, stream>>>(loraA, scale, a32);
  k_convert_w8<<<2048, 256, 0, stream>>>(wq, flag, wb8);
  k_lora_T<<<1024, 256, 0, stream>>>(xb, bb, tpart);
  k_reduce_T<<<1024, 256, 0, stream>>>(tpart, t32);
  k_gemm8<<<512, 1024, 0, stream>>>(xb, wb8, t32, a32, scale, bias, out);

  (void)in_sizes; (void)n_in; (void)out_size; (void)ws_size;
}